// Round 2
// baseline (175.359 us; speedup 1.0000x reference)
//
#include <hip/hip_runtime.h>
#include <math.h>

#define VOCAB 100000
#define DIM   128
#define BATCH 16384
#define CMAX  10
#define KNEG  5
#define NSCORE (CMAX + KNEG)

// Numerically stable log(sigmoid(x)) = min(x,0) - log1p(exp(-|x|))
__device__ __forceinline__ float log_sigmoid(float x) {
    return fminf(x, 0.0f) - log1pf(expf(-fabsf(x)));
}

__global__ void zero_out_kernel(float* out) {
    if (threadIdx.x < 2) out[threadIdx.x] = 0.0f;
}

// One half-wave (32 lanes) per sample: 32 lanes x float4 = 512 B = one full
// embedding row per global_load_dwordx4. 256-thread block -> 8 samples/block.
//
// Key change vs R1: all 15 out_emb row loads are staged into a register array
// (rv[15], 60 VGPRs) in a dedicated unrolled loop, so the compiler issues all
// 16 gathers back-to-back (memory-level parallelism) instead of the R1
// load->waitcnt->fma serial chain (VGPR_Count was 36 => ~1 load in flight).
__global__ __launch_bounds__(256) void sg_kernel(
    const int*   __restrict__ tgt,
    const int*   __restrict__ ctx,
    const int*   __restrict__ lens,
    const int*   __restrict__ neg,
    const float* __restrict__ in_emb,
    const float* __restrict__ out_emb,
    float*       __restrict__ out)
{
    const int tid  = threadIdx.x;
    const int lane = tid & 63;
    const int half = lane >> 5;       // which half-wave
    const int sub  = lane & 31;       // lane within half-wave
    const int waveInBlock = tid >> 6; // 0..3
    const int b = blockIdx.x * 8 + waveInBlock * 2 + half;   // sample index < BATCH

    // ---- one index load per lane, then broadcast via shfl (replaces 15
    //      broadcast VMEM loads per sample) ----
    int myword = 0;
    if (sub < CMAX)        myword = ctx[b * CMAX + sub];
    else if (sub < NSCORE) myword = neg[b * KNEG + (sub - CMAX)];

    const int t_word = tgt[b];

    int words[NSCORE];
#pragma unroll
    for (int j = 0; j < NSCORE; ++j)
        words[j] = __shfl(myword, half * 32 + j, 64);

    // ---- gather target row + all 15 score rows, ALL loads in flight ----
    const float4 tv = ((const float4*)(in_emb + (size_t)t_word * DIM))[sub];

    float4 rv[NSCORE];
#pragma unroll
    for (int j = 0; j < NSCORE; ++j)
        rv[j] = ((const float4*)(out_emb + (size_t)words[j] * DIM))[sub];

    float part[NSCORE];
#pragma unroll
    for (int j = 0; j < NSCORE; ++j)
        part[j] = tv.x * rv[j].x + tv.y * rv[j].y + tv.z * rv[j].z + tv.w * rv[j].w;

    // ---- butterfly reduce each score across the 32 lanes of the half-wave ----
    // xor masks 16,8,4,2,1 never cross the half-wave boundary within a wave64.
#pragma unroll
    for (int j = 0; j < NSCORE; ++j) {
#pragma unroll
        for (int m = 16; m >= 1; m >>= 1)
            part[j] += __shfl_xor(part[j], m, 64);
    }

    // ---- per-sample loss terms (all 32 lanes hold identical scores) ----
    const int len = lens[b];
    float pos_acc = 0.0f;
#pragma unroll
    for (int c = 0; c < CMAX; ++c)
        if (c < len) pos_acc += log_sigmoid(part[c]);
    float neg_acc = 0.0f;
#pragma unroll
    for (int k = 0; k < KNEG; ++k)
        neg_acc += log_sigmoid(-part[CMAX + k]);

    float pos_per = 0.0f, neg_per = 0.0f;
    if (len > 0) {
        pos_per = -pos_acc / (float)len;
        neg_per = -neg_acc * (1.0f / KNEG);
    }

    // ---- block reduce (8 samples) then one atomic pair per block ----
    __shared__ float s_pos[8];
    __shared__ float s_neg[8];
    if (sub == 0) {
        const int slot = waveInBlock * 2 + half;
        s_pos[slot] = pos_per;
        s_neg[slot] = neg_per;
    }
    __syncthreads();
    if (tid == 0) {
        float ps = 0.0f, ns = 0.0f;
#pragma unroll
        for (int i = 0; i < 8; ++i) { ps += s_pos[i]; ns += s_neg[i]; }
        atomicAdd(&out[0], ps * (1.0f / BATCH));
        atomicAdd(&out[1], ns * (1.0f / BATCH));
    }
}

extern "C" void kernel_launch(void* const* d_in, const int* in_sizes, int n_in,
                              void* d_out, int out_size, void* d_ws, size_t ws_size,
                              hipStream_t stream) {
    const int*   tgt     = (const int*)  d_in[0];
    const int*   ctx     = (const int*)  d_in[1];
    const int*   lens    = (const int*)  d_in[2];
    const int*   neg     = (const int*)  d_in[3];
    const float* in_emb  = (const float*)d_in[4];
    const float* out_emb = (const float*)d_in[5];
    float* out = (float*)d_out;

    // d_out is re-poisoned to 0xAA before every timed launch -> zero it first.
    zero_out_kernel<<<1, 64, 0, stream>>>(out);
    sg_kernel<<<BATCH / 8, 256, 0, stream>>>(tgt, ctx, lens, neg, in_emb, out_emb, out);
}

// Round 3
// 172.427 us; speedup vs baseline: 1.0170x; 1.0170x over previous
//
#include <hip/hip_runtime.h>
#include <math.h>
#include <stdint.h>

#define VOCAB 100000
#define DIM   128
#define BATCH 16384
#define CMAX  10
#define KNEG  5
#define NSCORE (CMAX + KNEG)

typedef float f32x4 __attribute__((ext_vector_type(4)));

// Numerically stable log(sigmoid(x)) = min(x,0) - log1p(exp(-|x|))
__device__ __forceinline__ float log_sigmoid(float x) {
    return fminf(x, 0.0f) - log1pf(expf(-fabsf(x)));
}

__global__ void zero_out_kernel(float* out) {
    if (threadIdx.x < 2) out[threadIdx.x] = 0.0f;
}

// One half-wave (32 lanes) per sample: 32 lanes x float4 = 512 B = one full
// embedding row per global_load_dwordx4.
//
// R3 key change: the 16 row gathers (tv + 15 rv) are issued via inline-asm
// global_load_dwordx4 (saddr form) so ALL 16 are in flight before a single
// s_waitcnt vmcnt(0). R1/R2 showed the compiler re-fuses load+use at VGPR=36
// (one load in flight -> serial latency chain -> 72-95 us). The waitcnt asm
// takes every loaded value as "+v" so no use can be scheduled before it.
__global__ __launch_bounds__(256) void sg_kernel(
    const int*   __restrict__ tgt,
    const int*   __restrict__ ctx,
    const int*   __restrict__ lens,
    const int*   __restrict__ neg,
    const float* __restrict__ in_emb,
    const float* __restrict__ out_emb,
    float*       __restrict__ out)
{
    const int tid  = threadIdx.x;
    const int lane = tid & 63;
    const int half = lane >> 5;       // which half-wave
    const int sub  = lane & 31;       // lane within half-wave
    const int waveInBlock = tid >> 6; // 0..3
    const int b = blockIdx.x * 8 + waveInBlock * 2 + half;   // sample index < BATCH

    // ---- index loads (independent, compiler batches them) ----
    const int t_word = tgt[b];
    const int len    = lens[b];
    int words[NSCORE];
#pragma unroll
    for (int c = 0; c < CMAX; ++c) words[c] = ctx[b * CMAX + c];
#pragma unroll
    for (int k = 0; k < KNEG; ++k) words[CMAX + k] = neg[b * KNEG + k];

    // ---- issue ALL 16 row gathers, then one waitcnt ----
    const uint32_t sub16 = (uint32_t)sub * 16u;   // byte offset of this lane's float4

    f32x4 tv;
    {
        uint32_t off = (uint32_t)t_word * (DIM * 4u) + sub16;
        asm volatile("global_load_dwordx4 %0, %1, %2"
                     : "=v"(tv) : "v"(off), "s"(in_emb));
    }
    f32x4 rv[NSCORE];
#pragma unroll
    for (int j = 0; j < NSCORE; ++j) {
        uint32_t off = (uint32_t)words[j] * (DIM * 4u) + sub16;
        asm volatile("global_load_dwordx4 %0, %1, %2"
                     : "=v"(rv[j]) : "v"(off), "s"(out_emb));
    }
    // Single drain; "+v" on every loaded value = uses cannot move above this.
    asm volatile("s_waitcnt vmcnt(0)"
                 : "+v"(tv),
                   "+v"(rv[0]), "+v"(rv[1]), "+v"(rv[2]), "+v"(rv[3]),
                   "+v"(rv[4]), "+v"(rv[5]), "+v"(rv[6]), "+v"(rv[7]),
                   "+v"(rv[8]), "+v"(rv[9]), "+v"(rv[10]), "+v"(rv[11]),
                   "+v"(rv[12]), "+v"(rv[13]), "+v"(rv[14])
                 :
                 : "memory");

    float part[NSCORE];
#pragma unroll
    for (int j = 0; j < NSCORE; ++j)
        part[j] = tv.x * rv[j].x + tv.y * rv[j].y + tv.z * rv[j].z + tv.w * rv[j].w;

    // ---- butterfly reduce each score across the 32 lanes of the half-wave ----
    // xor masks 16,8,4,2,1 never cross the half-wave boundary within a wave64.
#pragma unroll
    for (int j = 0; j < NSCORE; ++j) {
#pragma unroll
        for (int m = 16; m >= 1; m >>= 1)
            part[j] += __shfl_xor(part[j], m, 64);
    }

    // ---- per-sample loss terms (all 32 lanes hold identical scores) ----
    float pos_acc = 0.0f;
#pragma unroll
    for (int c = 0; c < CMAX; ++c)
        if (c < len) pos_acc += log_sigmoid(part[c]);
    float neg_acc = 0.0f;
#pragma unroll
    for (int k = 0; k < KNEG; ++k)
        neg_acc += log_sigmoid(-part[CMAX + k]);

    float pos_per = 0.0f, neg_per = 0.0f;
    if (len > 0) {
        pos_per = -pos_acc / (float)len;
        neg_per = -neg_acc * (1.0f / KNEG);
    }

    // ---- block reduce (8 samples) then one atomic pair per block ----
    __shared__ float s_pos[8];
    __shared__ float s_neg[8];
    if (sub == 0) {
        const int slot = waveInBlock * 2 + half;
        s_pos[slot] = pos_per;
        s_neg[slot] = neg_per;
    }
    __syncthreads();
    if (tid == 0) {
        float ps = 0.0f, ns = 0.0f;
#pragma unroll
        for (int i = 0; i < 8; ++i) { ps += s_pos[i]; ns += s_neg[i]; }
        atomicAdd(&out[0], ps * (1.0f / BATCH));
        atomicAdd(&out[1], ns * (1.0f / BATCH));
    }
}

extern "C" void kernel_launch(void* const* d_in, const int* in_sizes, int n_in,
                              void* d_out, int out_size, void* d_ws, size_t ws_size,
                              hipStream_t stream) {
    const int*   tgt     = (const int*)  d_in[0];
    const int*   ctx     = (const int*)  d_in[1];
    const int*   lens    = (const int*)  d_in[2];
    const int*   neg     = (const int*)  d_in[3];
    const float* in_emb  = (const float*)d_in[4];
    const float* out_emb = (const float*)d_in[5];
    float* out = (float*)d_out;

    // d_out is re-poisoned to 0xAA before every timed launch -> zero it first.
    zero_out_kernel<<<1, 64, 0, stream>>>(out);
    sg_kernel<<<BATCH / 8, 256, 0, stream>>>(tgt, ctx, lens, neg, in_emb, out_emb, out);
}

// Round 4
// 154.108 us; speedup vs baseline: 1.1379x; 1.1189x over previous
//
#include <hip/hip_runtime.h>
#include <math.h>
#include <stdint.h>

#define VOCAB 100000
#define DIM   128
#define BATCH 16384
#define CMAX  10
#define KNEG  5
#define NSCORE (CMAX + KNEG)
#define JPAD  16            // padded scores per sample (j=15 is a dummy slot)

// Numerically stable log(sigmoid(x)) = min(x,0) - log1p(exp(-|x|))
__device__ __forceinline__ float log_sigmoid(float x) {
    return fminf(x, 0.0f) - log1pf(expf(-fabsf(x)));
}

__global__ void zero_out_kernel(float* out) {
    if (threadIdx.x < 2) out[threadIdx.x] = 0.0f;
}

// ---------------------------------------------------------------------------
// Kernel A: one half-wave (32 lanes) per (sample b, score j) unit.
// 262,144 independent units -> 65,536 waves (8x R1's wave supply), each with a
// SHORT pipeline: idx loads -> two coalesced 512B row gathers -> dot ->
// 5-step butterfly -> one float store. R1-R3 showed 8192 long-pipeline waves
// leave the machine wave-starved (Occupancy ~= VALUBusy ~= 30%).
// ---------------------------------------------------------------------------
__global__ __launch_bounds__(256) void score_kernel(
    const int*   __restrict__ tgt,
    const int*   __restrict__ ctx,
    const int*   __restrict__ neg,
    const float* __restrict__ in_emb,
    const float* __restrict__ out_emb,
    float*       __restrict__ scores)   // [BATCH * JPAD]
{
    const int tid    = threadIdx.x;
    const int sub    = tid & 31;                              // lane in half-wave
    const int unit   = (blockIdx.x * 256 + tid) >> 5;         // global (b,j) id
    const int b      = unit >> 4;                             // sample
    const int j      = unit & 15;                             // score slot

    int word;
    if (j < CMAX)        word = ctx[b * CMAX + j];
    else if (j < NSCORE) word = neg[b * KNEG + (j - CMAX)];
    else                 word = 0;                            // dummy slot
    const int t_word = tgt[b];

    // Two independent coalesced row gathers (32 lanes x float4 = 512 B each).
    const float4 tv = ((const float4*)(in_emb  + (size_t)t_word * DIM))[sub];
    const float4 rv = ((const float4*)(out_emb + (size_t)word   * DIM))[sub];

    float p = tv.x * rv.x + tv.y * rv.y + tv.z * rv.z + tv.w * rv.w;

    // Butterfly across the 32 lanes of the half-wave (masks <=16 stay inside).
#pragma unroll
    for (int m = 16; m >= 1; m >>= 1)
        p += __shfl_xor(p, m, 64);

    if (sub == 0) scores[unit] = p;
}

// ---------------------------------------------------------------------------
// Kernel B: one thread per sample. Transcendental work is done once per
// sample (was redundantly on 32 lanes). Reads 1 MB of scores from L2.
// ---------------------------------------------------------------------------
__global__ __launch_bounds__(256) void loss_kernel(
    const float* __restrict__ scores,   // [BATCH * JPAD]
    const int*   __restrict__ lens,
    float*       __restrict__ out)
{
    const int tid = threadIdx.x;
    const int b   = blockIdx.x * 256 + tid;   // 64 blocks cover BATCH exactly

    const int len = lens[b];
    const float* s = scores + (size_t)b * JPAD;

    float sc[NSCORE];
#pragma unroll
    for (int j = 0; j < NSCORE; ++j) sc[j] = s[j];

    float pos_acc = 0.0f;
#pragma unroll
    for (int c = 0; c < CMAX; ++c)
        if (c < len) pos_acc += log_sigmoid(sc[c]);
    float neg_acc = 0.0f;
#pragma unroll
    for (int k = 0; k < KNEG; ++k)
        neg_acc += log_sigmoid(-sc[CMAX + k]);

    float pos_per = 0.0f, neg_per = 0.0f;
    if (len > 0) {
        pos_per = -pos_acc / (float)len;
        neg_per = -neg_acc * (1.0f / KNEG);
    }

    // wave reduction (64 lanes), then LDS across the 4 waves, then atomics
#pragma unroll
    for (int m = 32; m >= 1; m >>= 1) {
        pos_per += __shfl_xor(pos_per, m, 64);
        neg_per += __shfl_xor(neg_per, m, 64);
    }
    __shared__ float s_pos[4];
    __shared__ float s_neg[4];
    const int wave = tid >> 6;
    if ((tid & 63) == 0) { s_pos[wave] = pos_per; s_neg[wave] = neg_per; }
    __syncthreads();
    if (tid == 0) {
        float ps = s_pos[0] + s_pos[1] + s_pos[2] + s_pos[3];
        float ns = s_neg[0] + s_neg[1] + s_neg[2] + s_neg[3];
        atomicAdd(&out[0], ps * (1.0f / BATCH));
        atomicAdd(&out[1], ns * (1.0f / BATCH));
    }
}

extern "C" void kernel_launch(void* const* d_in, const int* in_sizes, int n_in,
                              void* d_out, int out_size, void* d_ws, size_t ws_size,
                              hipStream_t stream) {
    const int*   tgt     = (const int*)  d_in[0];
    const int*   ctx     = (const int*)  d_in[1];
    const int*   lens    = (const int*)  d_in[2];
    const int*   neg     = (const int*)  d_in[3];
    const float* in_emb  = (const float*)d_in[4];
    const float* out_emb = (const float*)d_in[5];
    float* out    = (float*)d_out;
    float* scores = (float*)d_ws;       // BATCH*JPAD*4 = 1 MiB scratch

    // d_out is re-poisoned to 0xAA before every timed launch -> zero it first.
    zero_out_kernel<<<1, 64, 0, stream>>>(out);

    // 262,144 units, 8 units (of 32 lanes) per 256-thread block.
    score_kernel<<<(BATCH * JPAD) / 8, 256, 0, stream>>>(
        tgt, ctx, neg, in_emb, out_emb, scores);

    loss_kernel<<<BATCH / 256, 256, 0, stream>>>(scores, lens, out);
}

// Round 5
// 150.149 us; speedup vs baseline: 1.1679x; 1.0264x over previous
//
#include <hip/hip_runtime.h>
#include <math.h>
#include <stdint.h>

#define VOCAB 100000
#define DIM   128
#define BATCH 16384
#define CMAX  10
#define KNEG  5
#define NSCORE (CMAX + KNEG)
#define JPAD  16            // padded scores per sample (j=15 is a dummy slot)

// Numerically stable log(sigmoid(x)) = min(x,0) - log1p(exp(-|x|))
__device__ __forceinline__ float log_sigmoid(float x) {
    return fminf(x, 0.0f) - log1pf(expf(-fabsf(x)));
}

// DPP-based 32-lane sum: after these 5 dependent VALU adds, lane 31 holds
// sum(lanes 0..31) and lane 63 holds sum(lanes 32..63). Replaces the 5-deep
// ds_swizzle butterfly (~120 cyc/step DS round-trips -> ~8 cyc/step VALU).
// update_dpp(old=0,...) with bound_ctrl=false: invalid source lanes take old
// (0), so they just add 0.
#define DPP_ADD_STEP(v, ctrl)                                                  \
    v += __int_as_float(__builtin_amdgcn_update_dpp(                           \
        0, __float_as_int(v), (ctrl), 0xF, 0xF, false))

__device__ __forceinline__ float dpp_reduce32_to_lane31(float v) {
    DPP_ADD_STEP(v, 0x111);  // row_shr:1
    DPP_ADD_STEP(v, 0x112);  // row_shr:2
    DPP_ADD_STEP(v, 0x114);  // row_shr:4
    DPP_ADD_STEP(v, 0x118);  // row_shr:8   -> lane 15/31/47/63 = row sums
    DPP_ADD_STEP(v, 0x142);  // row_bcast:15 -> lane 31 += lane 15, lane 63 += lane 47
    return v;
}

// ---------------------------------------------------------------------------
// Kernel A: one half-wave (32 lanes) per (sample b, score j) unit.
// 262,144 independent units -> 65,536 waves. Short per-unit pipeline:
// idx loads -> two coalesced 512B row gathers -> dot -> 5 DPP adds -> store.
// Block 0 also zeroes out[0..1] (d_out is re-poisoned before every launch);
// safe because only the subsequent loss_kernel reads/writes out.
// ---------------------------------------------------------------------------
__global__ __launch_bounds__(256) void score_kernel(
    const int*   __restrict__ tgt,
    const int*   __restrict__ ctx,
    const int*   __restrict__ neg,
    const float* __restrict__ in_emb,
    const float* __restrict__ out_emb,
    float*       __restrict__ scores,   // [BATCH * JPAD]
    float*       __restrict__ out)
{
    const int tid  = threadIdx.x;
    const int sub  = tid & 31;                              // lane in half-wave
    const int unit = (blockIdx.x * 256 + tid) >> 5;         // global (b,j) id
    const int b    = unit >> 4;                             // sample
    const int j    = unit & 15;                             // score slot

    if (blockIdx.x == 0 && tid < 2) out[tid] = 0.0f;

    int word;
    if (j < CMAX)        word = ctx[b * CMAX + j];
    else if (j < NSCORE) word = neg[b * KNEG + (j - CMAX)];
    else                 word = 0;                          // dummy slot
    const int t_word = tgt[b];

    // Two independent coalesced row gathers (32 lanes x float4 = 512 B each).
    const float4 tv = ((const float4*)(in_emb  + (size_t)t_word * DIM))[sub];
    const float4 rv = ((const float4*)(out_emb + (size_t)word   * DIM))[sub];

    float p = tv.x * rv.x + tv.y * rv.y + tv.z * rv.z + tv.w * rv.w;

    p = dpp_reduce32_to_lane31(p);

    // lane 31 holds the sum for the even unit, lane 63 for the odd unit.
    if (sub == 31) scores[unit] = p;
}

// ---------------------------------------------------------------------------
// Kernel B: one thread per sample. Reads 1 MB of scores from L2.
// ---------------------------------------------------------------------------
__global__ __launch_bounds__(256) void loss_kernel(
    const float* __restrict__ scores,   // [BATCH * JPAD]
    const int*   __restrict__ lens,
    float*       __restrict__ out)
{
    const int tid = threadIdx.x;
    const int b   = blockIdx.x * 256 + tid;   // 64 blocks cover BATCH exactly

    const int len = lens[b];
    const float* s = scores + (size_t)b * JPAD;

    float sc[NSCORE];
#pragma unroll
    for (int j = 0; j < NSCORE; ++j) sc[j] = s[j];

    float pos_acc = 0.0f;
#pragma unroll
    for (int c = 0; c < CMAX; ++c)
        if (c < len) pos_acc += log_sigmoid(sc[c]);
    float neg_acc = 0.0f;
#pragma unroll
    for (int k = 0; k < KNEG; ++k)
        neg_acc += log_sigmoid(-sc[CMAX + k]);

    float pos_per = 0.0f, neg_per = 0.0f;
    if (len > 0) {
        pos_per = -pos_acc / (float)len;
        neg_per = -neg_acc * (1.0f / KNEG);
    }

    // wave reduction (64 lanes), then LDS across the 4 waves, then atomics
#pragma unroll
    for (int m = 32; m >= 1; m >>= 1) {
        pos_per += __shfl_xor(pos_per, m, 64);
        neg_per += __shfl_xor(neg_per, m, 64);
    }
    __shared__ float s_pos[4];
    __shared__ float s_neg[4];
    const int wave = tid >> 6;
    if ((tid & 63) == 0) { s_pos[wave] = pos_per; s_neg[wave] = neg_per; }
    __syncthreads();
    if (tid == 0) {
        float ps = s_pos[0] + s_pos[1] + s_pos[2] + s_pos[3];
        float ns = s_neg[0] + s_neg[1] + s_neg[2] + s_neg[3];
        atomicAdd(&out[0], ps * (1.0f / BATCH));
        atomicAdd(&out[1], ns * (1.0f / BATCH));
    }
}

extern "C" void kernel_launch(void* const* d_in, const int* in_sizes, int n_in,
                              void* d_out, int out_size, void* d_ws, size_t ws_size,
                              hipStream_t stream) {
    const int*   tgt     = (const int*)  d_in[0];
    const int*   ctx     = (const int*)  d_in[1];
    const int*   lens    = (const int*)  d_in[2];
    const int*   neg     = (const int*)  d_in[3];
    const float* in_emb  = (const float*)d_in[4];
    const float* out_emb = (const float*)d_in[5];
    float* out    = (float*)d_out;
    float* scores = (float*)d_ws;       // BATCH*JPAD*4 = 1 MiB scratch

    // 262,144 units, 8 units (of 32 lanes) per 256-thread block.
    score_kernel<<<(BATCH * JPAD) / 8, 256, 0, stream>>>(
        tgt, ctx, neg, in_emb, out_emb, scores, out);

    loss_kernel<<<BATCH / 256, 256, 0, stream>>>(scores, lens, out);
}

// Round 6
// 135.994 us; speedup vs baseline: 1.2895x; 1.1041x over previous
//
#include <hip/hip_runtime.h>
#include <math.h>
#include <stdint.h>

#define VOCAB 100000
#define DIM   128
#define BATCH 16384
#define CMAX  10
#define KNEG  5
#define NSCORE (CMAX + KNEG)
#define JPAD  16            // padded scores per sample (j=15 is a dummy slot)

typedef float f32x4 __attribute__((ext_vector_type(4)));

// Numerically stable log(sigmoid(x)) = min(x,0) - log1p(exp(-|x|))
__device__ __forceinline__ float log_sigmoid(float x) {
    return fminf(x, 0.0f) - log1pf(expf(-fabsf(x)));
}

// DPP-based 32-lane sum: after 5 dependent VALU adds, lane 31 holds
// sum(lanes 0..31) and lane 63 holds sum(lanes 32..63).
#define DPP_ADD_STEP(v, ctrl)                                                  \
    v += __int_as_float(__builtin_amdgcn_update_dpp(                           \
        0, __float_as_int(v), (ctrl), 0xF, 0xF, false))

__device__ __forceinline__ float dpp_reduce32_to_lane31(float v) {
    DPP_ADD_STEP(v, 0x111);  // row_shr:1
    DPP_ADD_STEP(v, 0x112);  // row_shr:2
    DPP_ADD_STEP(v, 0x114);  // row_shr:4
    DPP_ADD_STEP(v, 0x118);  // row_shr:8
    DPP_ADD_STEP(v, 0x142);  // row_bcast:15
    return v;
}

// ---------------------------------------------------------------------------
// Kernel A: one half-wave (32 lanes) per (sample b, j-group g) task; each task
// computes 4 scores j = g*4 .. g*4+3. The 5 row gathers (tv + rv[0..3]) are
// issued via inline asm so ALL are in flight before one s_waitcnt vmcnt(0)
// (R3-proven mechanism, now applied at 74% occupancy where R1->R4 showed
// concurrency is the binding resource). t-row gathered once per 4 scores
// (was once per score) -> L1-level traffic 268 -> 167 MB.
// 65,536 tasks -> 8192 blocks of 256 threads.
// ---------------------------------------------------------------------------
__global__ __launch_bounds__(256) void score_kernel(
    const int*   __restrict__ tgt,
    const int*   __restrict__ ctx,
    const int*   __restrict__ neg,
    const float* __restrict__ in_emb,
    const float* __restrict__ out_emb,
    float*       __restrict__ scores,   // [BATCH * JPAD]
    float*       __restrict__ out)
{
    const int tid  = threadIdx.x;
    const int sub  = tid & 31;                              // lane in half-wave
    const int task = (blockIdx.x * 256 + tid) >> 5;         // global (b,g) id
    const int b    = task >> 2;                             // sample
    const int g    = task & 3;                              // j-group
    const int j0   = g * 4;

    if (blockIdx.x == 0 && tid < 2) out[tid] = 0.0f;

    // ---- index loads (independent; uniform within half-wave) ----
    const int t_word = tgt[b];
    int words[4];
#pragma unroll
    for (int jj = 0; jj < 4; ++jj) {
        const int j = j0 + jj;
        if (j < CMAX)        words[jj] = ctx[b * CMAX + j];
        else if (j < NSCORE) words[jj] = neg[b * KNEG + (j - CMAX)];
        else                 words[jj] = 0;                 // dummy slot j=15
    }

    // ---- issue all 5 row gathers, then one waitcnt ----
    const uint32_t sub16 = (uint32_t)sub * 16u;

    f32x4 tv;
    {
        uint32_t off = (uint32_t)t_word * (DIM * 4u) + sub16;
        asm volatile("global_load_dwordx4 %0, %1, %2"
                     : "=v"(tv) : "v"(off), "s"(in_emb));
    }
    f32x4 rv[4];
#pragma unroll
    for (int jj = 0; jj < 4; ++jj) {
        uint32_t off = (uint32_t)words[jj] * (DIM * 4u) + sub16;
        asm volatile("global_load_dwordx4 %0, %1, %2"
                     : "=v"(rv[jj]) : "v"(off), "s"(out_emb));
    }
    asm volatile("s_waitcnt vmcnt(0)"
                 : "+v"(tv), "+v"(rv[0]), "+v"(rv[1]), "+v"(rv[2]), "+v"(rv[3])
                 :
                 : "memory");

    // ---- 4 dots + 4 independent DPP reductions ----
    float p[4];
#pragma unroll
    for (int jj = 0; jj < 4; ++jj) {
        float d = tv.x * rv[jj].x + tv.y * rv[jj].y +
                  tv.z * rv[jj].z + tv.w * rv[jj].w;
        p[jj] = dpp_reduce32_to_lane31(d);
    }

    if (sub == 31) {
        float* s = scores + (size_t)b * JPAD + j0;
#pragma unroll
        for (int jj = 0; jj < 4; ++jj) s[jj] = p[jj];
    }
}

// ---------------------------------------------------------------------------
// Kernel B: one thread per sample. Reads 1 MB of scores from L2.
// ---------------------------------------------------------------------------
__global__ __launch_bounds__(256) void loss_kernel(
    const float* __restrict__ scores,   // [BATCH * JPAD]
    const int*   __restrict__ lens,
    float*       __restrict__ out)
{
    const int tid = threadIdx.x;
    const int b   = blockIdx.x * 256 + tid;   // 64 blocks cover BATCH exactly

    const int len = lens[b];
    const float* s = scores + (size_t)b * JPAD;

    float sc[NSCORE];
#pragma unroll
    for (int j = 0; j < NSCORE; ++j) sc[j] = s[j];

    float pos_acc = 0.0f;
#pragma unroll
    for (int c = 0; c < CMAX; ++c)
        if (c < len) pos_acc += log_sigmoid(sc[c]);
    float neg_acc = 0.0f;
#pragma unroll
    for (int k = 0; k < KNEG; ++k)
        neg_acc += log_sigmoid(-sc[CMAX + k]);

    float pos_per = 0.0f, neg_per = 0.0f;
    if (len > 0) {
        pos_per = -pos_acc / (float)len;
        neg_per = -neg_acc * (1.0f / KNEG);
    }

    // wave reduction (64 lanes), then LDS across the 4 waves, then atomics
#pragma unroll
    for (int m = 32; m >= 1; m >>= 1) {
        pos_per += __shfl_xor(pos_per, m, 64);
        neg_per += __shfl_xor(neg_per, m, 64);
    }
    __shared__ float s_pos[4];
    __shared__ float s_neg[4];
    const int wave = tid >> 6;
    if ((tid & 63) == 0) { s_pos[wave] = pos_per; s_neg[wave] = neg_per; }
    __syncthreads();
    if (tid == 0) {
        float ps = s_pos[0] + s_pos[1] + s_pos[2] + s_pos[3];
        float ns = s_neg[0] + s_neg[1] + s_neg[2] + s_neg[3];
        atomicAdd(&out[0], ps * (1.0f / BATCH));
        atomicAdd(&out[1], ns * (1.0f / BATCH));
    }
}

extern "C" void kernel_launch(void* const* d_in, const int* in_sizes, int n_in,
                              void* d_out, int out_size, void* d_ws, size_t ws_size,
                              hipStream_t stream) {
    const int*   tgt     = (const int*)  d_in[0];
    const int*   ctx     = (const int*)  d_in[1];
    const int*   lens    = (const int*)  d_in[2];
    const int*   neg     = (const int*)  d_in[3];
    const float* in_emb  = (const float*)d_in[4];
    const float* out_emb = (const float*)d_in[5];
    float* out    = (float*)d_out;
    float* scores = (float*)d_ws;       // BATCH*JPAD*4 = 1 MiB scratch

    // 65,536 (b,g) tasks, 8 tasks (of 32 lanes) per 256-thread block.
    score_kernel<<<(BATCH * 4) / 8, 256, 0, stream>>>(
        tgt, ctx, neg, in_emb, out_emb, scores, out);

    loss_kernel<<<BATCH / 256, 256, 0, stream>>>(scores, lens, out);
}